// Round 22
// baseline (235.350 us; speedup 1.0000x reference)
//
#include <hip/hip_runtime.h>

// SectorAttentionV2 on MI355X (gfx950) — round 22
//   Revert r21's gemm+prep merge (LDS over-allocation throttled scvt and
//   HBM contention crushed gemm: 146us merged vs 95us serial).
//   Keep r21's fused kernel (STAGE right after top barrier: ~68us).

typedef unsigned short u16;
typedef unsigned int u32;
typedef __attribute__((ext_vector_type(8))) short bf16x8;
typedef __attribute__((ext_vector_type(4))) float f32x4;
typedef __attribute__((ext_vector_type(8))) unsigned short u16x8;
typedef __attribute__((ext_vector_type(4))) unsigned short u16x4;
typedef __attribute__((ext_vector_type(4))) unsigned int u32x4;

__device__ __forceinline__ u16 f2b(float f) {
  u32 u = __float_as_uint(f);
  return (u16)((u + 0x7FFFu + ((u >> 16) & 1u)) >> 16);  // RNE
}
__device__ __forceinline__ float b2f(u16 v) { return __uint_as_float(((u32)v) << 16); }
__device__ __forceinline__ float b2f_lo(u32 d) { return __uint_as_float(d << 16); }
__device__ __forceinline__ float b2f_hi(u32 d) { return __uint_as_float(d & 0xffff0000u); }
__device__ __forceinline__ u32 cvt_pk(float lo, float hi) {
  u32 r;
  asm("v_cvt_pk_bf16_f32 %0, %1, %2" : "=v"(r) : "v"(lo), "v"(hi));
  return r;
}
#define GLDS(g, l)                                                                     \
  __builtin_amdgcn_global_load_lds((const __attribute__((address_space(1))) void*)(g), \
                                   (__attribute__((address_space(3))) void*)(l), 16, 0, 0)
#define SBAR() __builtin_amdgcn_sched_barrier(0)

// ---------------- prep: scvt (16384 blk) + wt (3x1024 blk) + bias (256 blk) ----------------
__global__ __launch_bounds__(256) void prep_kernel(
    const float* __restrict__ Wq, const float* __restrict__ Wk, const float* __restrict__ Wv,
    u16* __restrict__ Wt, const float* __restrict__ s, u16* __restrict__ sb,
    const float* __restrict__ xpos, const float* __restrict__ spos,
    const float* __restrict__ pw1, const float* __restrict__ pb1,
    const float* __restrict__ bng, const float* __restrict__ bnb,
    const float* __restrict__ bnm, const float* __restrict__ bnv,
    const float* __restrict__ pw2, const float* __restrict__ pb2, float* __restrict__ biasw) {
  int bid = (int)blockIdx.x;
  int t = threadIdx.x;
  if (bid < 16384) {
    size_t i = ((size_t)bid * 256 + t) * 8;
    float4 v0 = *(const float4*)(s + i);
    float4 v1 = *(const float4*)(s + i + 4);
    u32x4 pk;
    pk[0] = cvt_pk(v0.x, v0.y);
    pk[1] = cvt_pk(v0.z, v0.w);
    pk[2] = cvt_pk(v1.x, v1.y);
    pk[3] = cvt_pk(v1.z, v1.w);
    *(u32x4*)(sb + i) = pk;
  } else if (bid < 19456) {
    int r = bid - 16384;
    int mat = r >> 10, bx = r & 1023;
    const float* W = (mat == 0) ? Wq : (mat == 1) ? Wk : Wv;
    int g = bx * 256 + t;
    int n = g >> 9, k = g & 511;
    Wt[(size_t)mat * 262144 + g] = f2b(W[k * 512 + n]);
  } else {
    int bx = bid - 19456;
    int wl = t & 63, p = t >> 6;
    int n = bx * 64 + wl;
    int b = n >> 13, w = n & 8191;
    float Am[16], Bm[16], Cm[16];
#pragma unroll
    for (int m = 0; m < 16; ++m) {
      float scv = bng[m] * rsqrtf(bnv[m] + 1e-5f);
      Am[m] = pw1[2 * m] * scv;
      Bm[m] = pw1[2 * m + 1] * scv;
      Cm[m] = (pb1[m] - bnm[m]) * scv + bnb[m];
    }
    size_t xi = ((size_t)(b * 32768 + p * 8192 + w)) * 2;
    float xp0 = xpos[xi], xp1 = xpos[xi + 1];
#pragma unroll
    for (int ks = 0; ks < 4; ++ks) {
      size_t si = ((size_t)((b * 4 + ks) * 8192 + w)) * 2;
      float r0 = xp0 - spos[si];
      float r1 = xp1 - spos[si + 1];
      float o[8];
#pragma unroll
      for (int oo = 0; oo < 8; ++oo) o[oo] = pb2[oo];
#pragma unroll
      for (int m = 0; m < 16; ++m) {
        float h = fmaxf(Am[m] * r0 + Bm[m] * r1 + Cm[m], 0.f);
#pragma unroll
        for (int oo = 0; oo < 8; ++oo) o[oo] += pw2[oo * 16 + m] * h;
      }
#pragma unroll
      for (int oo = 0; oo < 8; ++oo)
        biasw[((size_t)(((b * 8 + oo) * 4 + p) * 4 + ks)) * 8192 + w] = o[oo];
    }
  }
}

// ---------------- Q GEMM (r18/r20): BM=128 BN=128 BK=32, dbuf + counted vmcnt ----------------
__global__ __launch_bounds__(256, 3) void gemm_kernel(const float* __restrict__ A,
                                                      const u16* __restrict__ Bt,
                                                      const float* __restrict__ biasv,
                                                      u16* __restrict__ Out) {
  __shared__ u16 lds[24576];
  const int t = threadIdx.x, lane = t & 63, wv = t >> 6;
  const int id = (int)blockIdx.x;
  const int lg = (id & 7) * 256 + (id >> 3);
  const int mt = (lg >> 2) * 128, nt = (lg & 3) * 128;
  const int fr = lane & 15, kg = lane >> 4;
  const int wm = (wv & 1) * 64, wn = (wv >> 1) * 64;

  const int arow = lane >> 3;
  const int agr = (lane & 7) ^ arow;
  const int brow = lane >> 2;
  const int bgr = (lane & 3) ^ (brow & 3) ^ ((brow >> 2) & 3);

  const float* Abase = A + (size_t)mt * 512;
  const u16* Bbase = Bt + (size_t)nt * 512;

  f32x4 acc[4][4];
#pragma unroll
  for (int i = 0; i < 4; ++i)
#pragma unroll
    for (int j = 0; j < 4; ++j) acc[i][j] = (f32x4){0.f, 0.f, 0.f, 0.f};

#define STAGEQ(buf, kt)                                                       \
  {                                                                           \
    u16* Ab_ = lds + (buf)*8192;                                              \
    u16* Bb_ = lds + 16384 + (buf)*4096;                                      \
    _Pragma("unroll") for (int ii = 0; ii < 4; ++ii) {                        \
      int inst = wv * 4 + ii;                                                 \
      GLDS(Abase + (size_t)(inst * 8 + arow) * 512 + (kt) + agr * 4,          \
           Ab_ + inst * 512);                                                 \
    }                                                                         \
    _Pragma("unroll") for (int ii = 0; ii < 2; ++ii) {                        \
      int inst = wv * 2 + ii;                                                 \
      GLDS(Bbase + (size_t)(inst * 16 + brow) * 512 + (kt) + bgr * 8,         \
           Bb_ + inst * 512);                                                 \
    }                                                                         \
  }

  STAGEQ(0, 0);

  for (int ki = 0; ki < 16; ++ki) {
    int cur = ki & 1;
    if (ki < 15) {
      STAGEQ(cur ^ 1, (ki + 1) * 32);
      asm volatile("s_waitcnt vmcnt(6)" ::: "memory");
    } else {
      asm volatile("s_waitcnt vmcnt(0)" ::: "memory");
    }
    SBAR();
    __builtin_amdgcn_s_barrier();
    SBAR();

    const u16* Ab = lds + cur * 8192;
    const u16* Bb = lds + 16384 + cur * 4096;
    bf16x8 af[4], bfr[4];
#pragma unroll
    for (int i = 0; i < 4; ++i) {
      int r = wm + i * 16 + fr;
      int p0 = (2 * kg) ^ (r & 7), p1 = p0 ^ 1;
      f32x4 a0 = *(const f32x4*)&Ab[r * 64 + p0 * 8];
      f32x4 a1 = *(const f32x4*)&Ab[r * 64 + p1 * 8];
      union { bf16x8 v; u32 w[4]; } uu;
      uu.w[0] = cvt_pk(a0[0], a0[1]);
      uu.w[1] = cvt_pk(a0[2], a0[3]);
      uu.w[2] = cvt_pk(a1[0], a1[1]);
      uu.w[3] = cvt_pk(a1[2], a1[3]);
      af[i] = uu.v;
    }
#pragma unroll
    for (int j = 0; j < 4; ++j) {
      int r = wn + j * 16 + fr;
      int pos = kg ^ (r & 3) ^ ((r >> 2) & 3);
      bfr[j] = *(const bf16x8*)&Bb[r * 32 + pos * 8];
    }
    __builtin_amdgcn_s_setprio(1);
#pragma unroll
    for (int i = 0; i < 4; ++i)
#pragma unroll
      for (int j = 0; j < 4; ++j)
        acc[i][j] = __builtin_amdgcn_mfma_f32_16x16x32_bf16(af[i], bfr[j], acc[i][j], 0, 0, 0);
    __builtin_amdgcn_s_setprio(0);

    SBAR();
    __builtin_amdgcn_s_barrier();
    SBAR();
  }
#undef STAGEQ

  u16* Clds = lds;
#pragma unroll
  for (int i = 0; i < 4; ++i)
#pragma unroll
    for (int r = 0; r < 4; ++r) {
      int row = wm + i * 16 + kg * 4 + r;
#pragma unroll
      for (int j = 0; j < 4; ++j) {
        int ch = wn + j * 16 + fr;
        Clds[row * 136 + ch] = f2b(acc[i][j][r] + biasv[nt + ch]);
      }
    }
  __syncthreads();
#pragma unroll
  for (int c = 0; c < 8; ++c) {
    int off = c * 2048 + t * 8;
    int row = off >> 7, col = off & 127;
    *(u16x8*)(Out + (size_t)(mt + row) * 512 + nt + col) = *(const u16x8*)&Clds[row * 136 + col];
  }
}

// ---------------- fused KV-projection + attention (r21: STAGE after top barrier) ----------------
// K-loop layout (bytes): S 3x16384 @0 ; W 3x8192 @49152 -> 73728
// Post-loop overlay: Xf 4096 @0 ; alds 4096 @4096 ; Klds [d][col][ks] @8192 (32768);
//                    Vlds [c][264] @40960 (33792) -> 74752 total
__global__ __launch_bounds__(512, 4) void fused_attn_kernel(
    const u16* __restrict__ sb, const u16* __restrict__ WtK, const u16* __restrict__ WtV,
    const float* __restrict__ bK, const float* __restrict__ bV,
    const u16* __restrict__ Qt, const float* __restrict__ biasw, float* __restrict__ out) {
  __shared__ __align__(16) char LDS[74752];
  float* Xf = (float*)LDS;
  float* alds = (float*)(LDS + 4096);
  u16* Klds = (u16*)(LDS + 8192);
  u16* Vlds = (u16*)(LDS + 40960);

  const int t = threadIdx.x, lane = t & 63, wv = t >> 6;
  const int i0 = (int)blockIdx.x;
  const int xcd = i0 & 7, qq = i0 >> 3;
  const int g = (qq >> 6) * 8 + xcd, inner = qq & 63;
  const int b = g >> 4, u = g & 15;
  const int cg = inner >> 3, nh = inner & 7;
  const int fr = lane & 15, kg = lane >> 4;
  const int p3p = wv >> 1, dh = wv & 1;
  const int mg = wv >> 1, ng = wv & 1;  // 4 m-groups x 2 n-groups

  f32x4 accK[4][2], accV[4][2];
#pragma unroll
  for (int i = 0; i < 4; ++i)
#pragma unroll
    for (int j = 0; j < 2; ++j) {
      accK[i][j] = (f32x4){0.f, 0.f, 0.f, 0.f};
      accV[i][j] = (f32x4){0.f, 0.f, 0.f, 0.f};
    }

  const int lgr = (lane & 3) ^ ((lane >> 3) & 3);

#define STAGEF(buf, kt)                                                                 \
  {                                                                                     \
    u16* Sb_ = (u16*)(LDS) + (buf)*8192;                                                \
    _Pragma("unroll") for (int ii = 0; ii < 2; ++ii) {                                  \
      int i = wv * 2 + ii;                                                              \
      int r = i * 16 + (lane >> 2);                                                     \
      int grow = nh * 4096 + (r >> 2) * 64 + (r & 3) * 16 + u;                          \
      GLDS(sb + (size_t)(b * 32768 + grow) * 512 + (kt) + lgr * 8, Sb_ + i * 512);      \
    }                                                                                   \
    {                                                                                   \
      const u16* wsrc = (wv < 4) ? WtK : WtV;                                           \
      u16* Wb_ = (u16*)(LDS + 49152 + (buf)*8192 + ((wv < 4) ? 0 : 4096));              \
      int i = wv & 3;                                                                   \
      int r = i * 16 + (lane >> 2);                                                     \
      GLDS(wsrc + (size_t)(cg * 64 + r) * 512 + (kt) + lgr * 8, Wb_ + i * 512);         \
    }                                                                                   \
  }

  STAGEF(0, 0);
  STAGEF(1, 32);

  for (int ki = 0; ki < 16; ++ki) {
    int cur = ki % 3;
    if (ki < 15) {
      asm volatile("s_waitcnt vmcnt(3)" ::: "memory");
    } else {
      asm volatile("s_waitcnt vmcnt(0)" ::: "memory");
    }
    SBAR();
    __builtin_amdgcn_s_barrier();
    SBAR();
    // prefetch tile ki+2 FIRST (max slack). Target buf (ki+2)%3 was last read
    // in iter ki-1; the barrier above proves all those reads retired.
    if (ki < 14) STAGEF((ki + 2) % 3, (ki + 2) * 32);
    SBAR();

    const u16* Sb = (const u16*)(LDS) + cur * 8192;
    const u16* Kb = (const u16*)(LDS + 49152 + cur * 8192);
    const u16* Vb = (const u16*)(LDS + 49152 + cur * 8192 + 4096);
    bf16x8 af[4];
#pragma unroll
    for (int i = 0; i < 4; ++i) {
      int r = mg * 64 + i * 16 + fr;
      int gpos = kg ^ ((fr >> 1) & 3);
      af[i] = *(const bf16x8*)&Sb[r * 32 + gpos * 8];
    }
    {
      bf16x8 bkf[2];
#pragma unroll
      for (int j = 0; j < 2; ++j) {
        int r = ng * 32 + j * 16 + fr;
        int gpos = kg ^ ((fr >> 1) & 3);
        bkf[j] = *(const bf16x8*)&Kb[r * 32 + gpos * 8];
      }
      __builtin_amdgcn_s_setprio(1);
#pragma unroll
      for (int i = 0; i < 4; ++i)
#pragma unroll
        for (int j = 0; j < 2; ++j)
          accK[i][j] = __builtin_amdgcn_mfma_f32_16x16x32_bf16(af[i], bkf[j], accK[i][j], 0, 0, 0);
      __builtin_amdgcn_s_setprio(0);
    }
    {
      bf16x8 bvf[2];
#pragma unroll
      for (int j = 0; j < 2; ++j) {
        int r = ng * 32 + j * 16 + fr;
        int gpos = kg ^ ((fr >> 1) & 3);
        bvf[j] = *(const bf16x8*)&Vb[r * 32 + gpos * 8];
      }
      __builtin_amdgcn_s_setprio(1);
#pragma unroll
      for (int i = 0; i < 4; ++i)
#pragma unroll
        for (int j = 0; j < 2; ++j)
          accV[i][j] = __builtin_amdgcn_mfma_f32_16x16x32_bf16(af[i], bvf[j], accV[i][j], 0, 0, 0);
      __builtin_amdgcn_s_setprio(0);
    }
    SBAR();
  }
#undef STAGEF

  // post-loop loads (overlap the overlay barrier)
  SBAR();
  float bkr[2], bvr[2];
#pragma unroll
  for (int j = 0; j < 2; ++j) {
    bkr[j] = bK[cg * 64 + ng * 32 + j * 16 + fr];
    bvr[j] = bV[cg * 64 + ng * 32 + j * 16 + fr];
  }
  u32x4 qv[4];
  {
    const u16* qp =
        Qt + (size_t)(b * 32768 + p3p * 8192 + u * 512 + cg * 64 + lane) * 512 + nh * 64 + dh * 32;
#pragma unroll
    for (int i = 0; i < 4; ++i) qv[i] = *(const u32x4*)(qp + i * 8);
  }
  float br[4];
  {
    const size_t bb = ((size_t)((b * 8 + nh) * 16 + p3p * 4)) * 8192 + u * 512 + cg * 64 + lane;
#pragma unroll
    for (int ks = 0; ks < 4; ++ks) br[ks] = biasw[bb + (size_t)ks * 8192];
  }
  SBAR();
  __builtin_amdgcn_s_barrier();  // overlay barrier
  SBAR();

  // ---- P2: panels -> LDS (K [d][col][ks] b64; V [c][256+8] b64) ----
#pragma unroll
  for (int i = 0; i < 4; ++i) {
    int d = mg * 16 + i * 4 + kg;
    int row0 = mg * 64 + i * 16 + kg * 4;
#pragma unroll
    for (int j = 0; j < 2; ++j) {
      int col = ng * 32 + j * 16 + fr;
      u16x4 kq, vq;
#pragma unroll
      for (int rr = 0; rr < 4; ++rr) {
        kq[rr] = f2b(accK[i][j][rr] + bkr[j]);
        vq[rr] = f2b(accV[i][j][rr] + bvr[j]);
      }
      *(u16x4*)&Klds[(d * 64 + col) * 4] = kq;
      *(u16x4*)&Vlds[col * 264 + row0] = vq;
    }
  }
  __syncthreads();

  // ---- P3: QK (lane=c, wave=(p,dh)); b64 K reads ----
  float sc[4] = {0.f, 0.f, 0.f, 0.f};
#pragma unroll
  for (int dd = 0; dd < 32; ++dd) {
    int d = dh * 32 + dd;
    u32 word = qv[dd >> 3][(dd >> 1) & 3];
    float qd = (dd & 1) ? b2f_hi(word) : b2f_lo(word);
    u16x4 kv4 = *(const u16x4*)&Klds[(d * 64 + lane) * 4];
#pragma unroll
    for (int ks = 0; ks < 4; ++ks) sc[ks] += qd * b2f(kv4[ks]);
  }
  if (dh == 1) {
#pragma unroll
    for (int ks = 0; ks < 4; ++ks) Xf[(p3p * 4 + ks) * 64 + lane] = sc[ks];
  }
  __syncthreads();

  if (dh == 0) {
    float sv[4];
#pragma unroll
    for (int ks = 0; ks < 4; ++ks)
      sv[ks] = (sc[ks] + Xf[(p3p * 4 + ks) * 64 + lane]) * 0.125f + br[ks];
    float mx = fmaxf(fmaxf(sv[0], sv[1]), fmaxf(sv[2], sv[3]));
    float e0 = __expf(sv[0] - mx), e1 = __expf(sv[1] - mx), e2 = __expf(sv[2] - mx),
          e3 = __expf(sv[3] - mx);
    float inv = 1.f / (e0 + e1 + e2 + e3);
#pragma unroll
    for (int ks = 0; ks < 4; ++ks) {
      float e = (ks == 0) ? e0 : (ks == 1) ? e1 : (ks == 2) ? e2 : e3;
      alds[(p3p * 4 + ks) * 64 + lane] = e * inv;
    }
  }
  __syncthreads();

  // ---- PV: lane = out channel; wave handles its (p, c-half) ----
  float* ob = out + (size_t)(b * 32768 + p3p * 8192 + u * 512 + cg * 64) * 512 + nh * 64 + lane;
#pragma unroll
  for (int cc = 0; cc < 32; ++cc) {
    int c = dh * 32 + cc;
    u16x4 vvv = *(const u16x4*)&Vlds[c * 264 + lane * 4];
    float a0 = alds[(p3p * 4 + 0) * 64 + c];
    float a1 = alds[(p3p * 4 + 1) * 64 + c];
    float a2 = alds[(p3p * 4 + 2) * 64 + c];
    float a3 = alds[(p3p * 4 + 3) * 64 + c];
    float o = a0 * b2f(vvv[0]) + a1 * b2f(vvv[1]) + a2 * b2f(vvv[2]) + a3 * b2f(vvv[3]);
    ob[(size_t)c * 512] = o;
  }
}

// ---------------- launch ----------------
extern "C" void kernel_launch(void* const* d_in, const int* in_sizes, int n_in,
                              void* d_out, int out_size, void* d_ws, size_t ws_size,
                              hipStream_t stream) {
  (void)in_sizes; (void)n_in; (void)out_size; (void)ws_size;
  const float* s     = (const float*)d_in[0];
  const float* x     = (const float*)d_in[1];
  const float* s_pos = (const float*)d_in[2];
  const float* x_pos = (const float*)d_in[3];
  const float* Wq = (const float*)d_in[4];  const float* bq = (const float*)d_in[5];
  const float* Wk = (const float*)d_in[6];  const float* bk = (const float*)d_in[7];
  const float* Wv = (const float*)d_in[8];  const float* bv = (const float*)d_in[9];
  const float* pw1 = (const float*)d_in[10]; const float* pb1 = (const float*)d_in[11];
  const float* bng = (const float*)d_in[12]; const float* bnb = (const float*)d_in[13];
  const float* bnm = (const float*)d_in[14]; const float* bnv = (const float*)d_in[15];
  const float* pw2 = (const float*)d_in[16]; const float* pb2 = (const float*)d_in[17];
  float* out = (float*)d_out;

  char* ws = (char*)d_ws;
  u16* Qt = (u16*)ws;                        // 67,108,864 B
  float* biasw = (float*)(ws + 67108864);    //  8,388,608 B
  u16* Wt = (u16*)(ws + 75497472);           //  1,572,864 B
  u16* sbuf = (u16*)(ws + 77070336);         // 67,108,864 B (s in bf16)

  prep_kernel<<<dim3(19712), 256, 0, stream>>>(Wq, Wk, Wv, Wt, s, sbuf, x_pos, s_pos, pw1, pb1,
                                               bng, bnb, bnm, bnv, pw2, pb2, biasw);
  gemm_kernel<<<dim3(2048), 256, 0, stream>>>(x, Wt, bq, Qt);
  fused_attn_kernel<<<dim3(2048), 512, 0, stream>>>(sbuf, Wt + 262144, Wt + 524288, bk, bv,
                                                    Qt, biasw, out);
}

// Round 23
// 218.088 us; speedup vs baseline: 1.0792x; 1.0792x over previous
//
#include <hip/hip_runtime.h>

// SectorAttentionV2 on MI355X (gfx950) — round 23
//   Restore r21 exactly: wt -> merged mid(gemm+scvt+bias) -> fused.
//   r21 was the wall-clock best (217.5us); r22's "revert the merge" was based
//   on profiler-perturbed per-dispatch times and regressed to 235us.

typedef unsigned short u16;
typedef unsigned int u32;
typedef __attribute__((ext_vector_type(8))) short bf16x8;
typedef __attribute__((ext_vector_type(4))) float f32x4;
typedef __attribute__((ext_vector_type(8))) unsigned short u16x8;
typedef __attribute__((ext_vector_type(4))) unsigned short u16x4;
typedef __attribute__((ext_vector_type(4))) unsigned int u32x4;

__device__ __forceinline__ u16 f2b(float f) {
  u32 u = __float_as_uint(f);
  return (u16)((u + 0x7FFFu + ((u >> 16) & 1u)) >> 16);  // RNE
}
__device__ __forceinline__ float b2f(u16 v) { return __uint_as_float(((u32)v) << 16); }
__device__ __forceinline__ float b2f_lo(u32 d) { return __uint_as_float(d << 16); }
__device__ __forceinline__ float b2f_hi(u32 d) { return __uint_as_float(d & 0xffff0000u); }
__device__ __forceinline__ u32 cvt_pk(float lo, float hi) {
  u32 r;
  asm("v_cvt_pk_bf16_f32 %0, %1, %2" : "=v"(r) : "v"(lo), "v"(hi));
  return r;
}
#define GLDS(g, l)                                                                     \
  __builtin_amdgcn_global_load_lds((const __attribute__((address_space(1))) void*)(g), \
                                   (__attribute__((address_space(3))) void*)(l), 16, 0, 0)
#define SBAR() __builtin_amdgcn_sched_barrier(0)

// ---------------- wt: W[k][n] f32 -> Wt[n][k] bf16 (x3) ----------------
__global__ __launch_bounds__(256) void wt_kernel(const float* __restrict__ Wq,
                                                 const float* __restrict__ Wk,
                                                 const float* __restrict__ Wv,
                                                 u16* __restrict__ Wt) {
  int bid = (int)blockIdx.x;
  int mat = bid >> 10, bx = bid & 1023;
  const float* W = (mat == 0) ? Wq : (mat == 1) ? Wk : Wv;
  int g = bx * 256 + threadIdx.x;
  int n = g >> 9, k = g & 511;
  Wt[(size_t)mat * 262144 + g] = f2b(W[k * 512 + n]);
}

// ---------------- mid: gemm (bid<2048) + scvt (2048..18431) + bias (18432..18687) ----------------
__global__ __launch_bounds__(256, 3) void mid_kernel(
    const float* __restrict__ A, const u16* __restrict__ Bt, const float* __restrict__ biasv,
    u16* __restrict__ Out, const float* __restrict__ s, u16* __restrict__ sb,
    const float* __restrict__ xpos, const float* __restrict__ spos,
    const float* __restrict__ pw1, const float* __restrict__ pb1,
    const float* __restrict__ bng, const float* __restrict__ bnb,
    const float* __restrict__ bnm, const float* __restrict__ bnv,
    const float* __restrict__ pw2, const float* __restrict__ pb2, float* __restrict__ biasw) {
  __shared__ u16 lds[24576];
  const int bid = (int)blockIdx.x;
  const int t = threadIdx.x;

  if (bid >= 2048) {
    if (bid < 18432) {
      // ---- scvt: s f32 -> bf16 ----
      size_t i = ((size_t)(bid - 2048) * 256 + t) * 8;
      float4 v0 = *(const float4*)(s + i);
      float4 v1 = *(const float4*)(s + i + 4);
      u32x4 pk;
      pk[0] = cvt_pk(v0.x, v0.y);
      pk[1] = cvt_pk(v0.z, v0.w);
      pk[2] = cvt_pk(v1.x, v1.y);
      pk[3] = cvt_pk(v1.z, v1.w);
      *(u32x4*)(sb + i) = pk;
    } else {
      // ---- bias MLP ----
      int bx = bid - 18432;
      int wl = t & 63, p = t >> 6;
      int n = bx * 64 + wl;
      int b = n >> 13, w = n & 8191;
      float Am[16], Bm[16], Cm[16];
#pragma unroll
      for (int m = 0; m < 16; ++m) {
        float scv = bng[m] * rsqrtf(bnv[m] + 1e-5f);
        Am[m] = pw1[2 * m] * scv;
        Bm[m] = pw1[2 * m + 1] * scv;
        Cm[m] = (pb1[m] - bnm[m]) * scv + bnb[m];
      }
      size_t xi = ((size_t)(b * 32768 + p * 8192 + w)) * 2;
      float xp0 = xpos[xi], xp1 = xpos[xi + 1];
#pragma unroll
      for (int ks = 0; ks < 4; ++ks) {
        size_t si = ((size_t)((b * 4 + ks) * 8192 + w)) * 2;
        float r0 = xp0 - spos[si];
        float r1 = xp1 - spos[si + 1];
        float o[8];
#pragma unroll
        for (int oo = 0; oo < 8; ++oo) o[oo] = pb2[oo];
#pragma unroll
        for (int m = 0; m < 16; ++m) {
          float h = fmaxf(Am[m] * r0 + Bm[m] * r1 + Cm[m], 0.f);
#pragma unroll
          for (int oo = 0; oo < 8; ++oo) o[oo] += pw2[oo * 16 + m] * h;
        }
#pragma unroll
        for (int oo = 0; oo < 8; ++oo)
          biasw[((size_t)(((b * 8 + oo) * 4 + p) * 4 + ks)) * 8192 + w] = o[oo];
      }
    }
    return;
  }

  // ---- gemm role (r18/r20 proven body) ----
  const int lane = t & 63, wv = t >> 6;
  const int lg = (bid & 7) * 256 + (bid >> 3);
  const int mt = (lg >> 2) * 128, nt = (lg & 3) * 128;
  const int fr = lane & 15, kg = lane >> 4;
  const int wm = (wv & 1) * 64, wn = (wv >> 1) * 64;

  const int arow = lane >> 3;
  const int agr = (lane & 7) ^ arow;
  const int brow = lane >> 2;
  const int bgr = (lane & 3) ^ (brow & 3) ^ ((brow >> 2) & 3);

  const float* Abase = A + (size_t)mt * 512;
  const u16* Bbase = Bt + (size_t)nt * 512;

  f32x4 acc[4][4];
#pragma unroll
  for (int i = 0; i < 4; ++i)
#pragma unroll
    for (int j = 0; j < 4; ++j) acc[i][j] = (f32x4){0.f, 0.f, 0.f, 0.f};

#define STAGEQ(buf, kt)                                                       \
  {                                                                           \
    u16* Ab_ = lds + (buf)*8192;                                              \
    u16* Bb_ = lds + 16384 + (buf)*4096;                                      \
    _Pragma("unroll") for (int ii = 0; ii < 4; ++ii) {                        \
      int inst = wv * 4 + ii;                                                 \
      GLDS(Abase + (size_t)(inst * 8 + arow) * 512 + (kt) + agr * 4,          \
           Ab_ + inst * 512);                                                 \
    }                                                                         \
    _Pragma("unroll") for (int ii = 0; ii < 2; ++ii) {                        \
      int inst = wv * 2 + ii;                                                 \
      GLDS(Bbase + (size_t)(inst * 16 + brow) * 512 + (kt) + bgr * 8,         \
           Bb_ + inst * 512);                                                 \
    }                                                                         \
  }

  STAGEQ(0, 0);

  for (int ki = 0; ki < 16; ++ki) {
    int cur = ki & 1;
    if (ki < 15) {
      STAGEQ(cur ^ 1, (ki + 1) * 32);
      asm volatile("s_waitcnt vmcnt(6)" ::: "memory");
    } else {
      asm volatile("s_waitcnt vmcnt(0)" ::: "memory");
    }
    SBAR();
    __builtin_amdgcn_s_barrier();
    SBAR();

    const u16* Ab = lds + cur * 8192;
    const u16* Bb = lds + 16384 + cur * 4096;
    bf16x8 af[4], bfr[4];
#pragma unroll
    for (int i = 0; i < 4; ++i) {
      int r = wm + i * 16 + fr;
      int p0 = (2 * kg) ^ (r & 7), p1 = p0 ^ 1;
      f32x4 a0 = *(const f32x4*)&Ab[r * 64 + p0 * 8];
      f32x4 a1 = *(const f32x4*)&Ab[r * 64 + p1 * 8];
      union { bf16x8 v; u32 w[4]; } uu;
      uu.w[0] = cvt_pk(a0[0], a0[1]);
      uu.w[1] = cvt_pk(a0[2], a0[3]);
      uu.w[2] = cvt_pk(a1[0], a1[1]);
      uu.w[3] = cvt_pk(a1[2], a1[3]);
      af[i] = uu.v;
    }
#pragma unroll
    for (int j = 0; j < 4; ++j) {
      int r = wn + j * 16 + fr;
      int pos = kg ^ (r & 3) ^ ((r >> 2) & 3);
      bfr[j] = *(const bf16x8*)&Bb[r * 32 + pos * 8];
    }
    __builtin_amdgcn_s_setprio(1);
#pragma unroll
    for (int i = 0; i < 4; ++i)
#pragma unroll
      for (int j = 0; j < 4; ++j)
        acc[i][j] = __builtin_amdgcn_mfma_f32_16x16x32_bf16(af[i], bfr[j], acc[i][j], 0, 0, 0);
    __builtin_amdgcn_s_setprio(0);

    SBAR();
    __builtin_amdgcn_s_barrier();
    SBAR();
  }
#undef STAGEQ

  u16* Clds = lds;
#pragma unroll
  for (int i = 0; i < 4; ++i)
#pragma unroll
    for (int r = 0; r < 4; ++r) {
      int row = wm + i * 16 + kg * 4 + r;
#pragma unroll
      for (int j = 0; j < 4; ++j) {
        int ch = wn + j * 16 + fr;
        Clds[row * 136 + ch] = f2b(acc[i][j][r] + biasv[nt + ch]);
      }
    }
  __syncthreads();
#pragma unroll
  for (int c = 0; c < 8; ++c) {
    int off = c * 2048 + t * 8;
    int row = off >> 7, col = off & 127;
    *(u16x8*)(Out + (size_t)(mt + row) * 512 + nt + col) = *(const u16x8*)&Clds[row * 136 + col];
  }
}

// ---------------- fused KV-projection + attention (64x32 wave tiles) ----------------
// K-loop layout (bytes): S 3x16384 @0 ; W 3x8192 @49152 -> 73728
// Post-loop overlay: Xf 4096 @0 ; alds 4096 @4096 ; Klds [d][col][ks] @8192 (32768);
//                    Vlds [c][264] @40960 (33792) -> 74752 total
__global__ __launch_bounds__(512, 4) void fused_attn_kernel(
    const u16* __restrict__ sb, const u16* __restrict__ WtK, const u16* __restrict__ WtV,
    const float* __restrict__ bK, const float* __restrict__ bV,
    const u16* __restrict__ Qt, const float* __restrict__ biasw, float* __restrict__ out) {
  __shared__ __align__(16) char LDS[74752];
  float* Xf = (float*)LDS;
  float* alds = (float*)(LDS + 4096);
  u16* Klds = (u16*)(LDS + 8192);
  u16* Vlds = (u16*)(LDS + 40960);

  const int t = threadIdx.x, lane = t & 63, wv = t >> 6;
  const int i0 = (int)blockIdx.x;
  const int xcd = i0 & 7, qq = i0 >> 3;
  const int g = (qq >> 6) * 8 + xcd, inner = qq & 63;
  const int b = g >> 4, u = g & 15;
  const int cg = inner >> 3, nh = inner & 7;
  const int fr = lane & 15, kg = lane >> 4;
  const int p3p = wv >> 1, dh = wv & 1;
  const int mg = wv >> 1, ng = wv & 1;  // 4 m-groups x 2 n-groups

  f32x4 accK[4][2], accV[4][2];
#pragma unroll
  for (int i = 0; i < 4; ++i)
#pragma unroll
    for (int j = 0; j < 2; ++j) {
      accK[i][j] = (f32x4){0.f, 0.f, 0.f, 0.f};
      accV[i][j] = (f32x4){0.f, 0.f, 0.f, 0.f};
    }

  const int lgr = (lane & 3) ^ ((lane >> 3) & 3);

#define STAGEF(buf, kt)                                                                 \
  {                                                                                     \
    u16* Sb_ = (u16*)(LDS) + (buf)*8192;                                                \
    _Pragma("unroll") for (int ii = 0; ii < 2; ++ii) {                                  \
      int i = wv * 2 + ii;                                                              \
      int r = i * 16 + (lane >> 2);                                                     \
      int grow = nh * 4096 + (r >> 2) * 64 + (r & 3) * 16 + u;                          \
      GLDS(sb + (size_t)(b * 32768 + grow) * 512 + (kt) + lgr * 8, Sb_ + i * 512);      \
    }                                                                                   \
    {                                                                                   \
      const u16* wsrc = (wv < 4) ? WtK : WtV;                                           \
      u16* Wb_ = (u16*)(LDS + 49152 + (buf)*8192 + ((wv < 4) ? 0 : 4096));              \
      int i = wv & 3;                                                                   \
      int r = i * 16 + (lane >> 2);                                                     \
      GLDS(wsrc + (size_t)(cg * 64 + r) * 512 + (kt) + lgr * 8, Wb_ + i * 512);         \
    }                                                                                   \
  }

  STAGEF(0, 0);
  STAGEF(1, 32);

  for (int ki = 0; ki < 16; ++ki) {
    int cur = ki % 3;
    if (ki < 15) {
      asm volatile("s_waitcnt vmcnt(3)" ::: "memory");
    } else {
      asm volatile("s_waitcnt vmcnt(0)" ::: "memory");
    }
    SBAR();
    __builtin_amdgcn_s_barrier();
    SBAR();
    // prefetch tile ki+2 FIRST (max slack). Target buf (ki+2)%3 was last read
    // in iter ki-1; the barrier above proves all those reads retired.
    if (ki < 14) STAGEF((ki + 2) % 3, (ki + 2) * 32);
    SBAR();

    const u16* Sb = (const u16*)(LDS) + cur * 8192;
    const u16* Kb = (const u16*)(LDS + 49152 + cur * 8192);
    const u16* Vb = (const u16*)(LDS + 49152 + cur * 8192 + 4096);
    bf16x8 af[4];
#pragma unroll
    for (int i = 0; i < 4; ++i) {
      int r = mg * 64 + i * 16 + fr;
      int gpos = kg ^ ((fr >> 1) & 3);
      af[i] = *(const bf16x8*)&Sb[r * 32 + gpos * 8];
    }
    {
      bf16x8 bkf[2];
#pragma unroll
      for (int j = 0; j < 2; ++j) {
        int r = ng * 32 + j * 16 + fr;
        int gpos = kg ^ ((fr >> 1) & 3);
        bkf[j] = *(const bf16x8*)&Kb[r * 32 + gpos * 8];
      }
      __builtin_amdgcn_s_setprio(1);
#pragma unroll
      for (int i = 0; i < 4; ++i)
#pragma unroll
        for (int j = 0; j < 2; ++j)
          accK[i][j] = __builtin_amdgcn_mfma_f32_16x16x32_bf16(af[i], bkf[j], accK[i][j], 0, 0, 0);
      __builtin_amdgcn_s_setprio(0);
    }
    {
      bf16x8 bvf[2];
#pragma unroll
      for (int j = 0; j < 2; ++j) {
        int r = ng * 32 + j * 16 + fr;
        int gpos = kg ^ ((fr >> 1) & 3);
        bvf[j] = *(const bf16x8*)&Vb[r * 32 + gpos * 8];
      }
      __builtin_amdgcn_s_setprio(1);
#pragma unroll
      for (int i = 0; i < 4; ++i)
#pragma unroll
        for (int j = 0; j < 2; ++j)
          accV[i][j] = __builtin_amdgcn_mfma_f32_16x16x32_bf16(af[i], bvf[j], accV[i][j], 0, 0, 0);
      __builtin_amdgcn_s_setprio(0);
    }
    SBAR();
  }
#undef STAGEF

  // post-loop loads (overlap the overlay barrier)
  SBAR();
  float bkr[2], bvr[2];
#pragma unroll
  for (int j = 0; j < 2; ++j) {
    bkr[j] = bK[cg * 64 + ng * 32 + j * 16 + fr];
    bvr[j] = bV[cg * 64 + ng * 32 + j * 16 + fr];
  }
  u32x4 qv[4];
  {
    const u16* qp =
        Qt + (size_t)(b * 32768 + p3p * 8192 + u * 512 + cg * 64 + lane) * 512 + nh * 64 + dh * 32;
#pragma unroll
    for (int i = 0; i < 4; ++i) qv[i] = *(const u32x4*)(qp + i * 8);
  }
  float br[4];
  {
    const size_t bb = ((size_t)((b * 8 + nh) * 16 + p3p * 4)) * 8192 + u * 512 + cg * 64 + lane;
#pragma unroll
    for (int ks = 0; ks < 4; ++ks) br[ks] = biasw[bb + (size_t)ks * 8192];
  }
  SBAR();
  __builtin_amdgcn_s_barrier();  // overlay barrier
  SBAR();

  // ---- P2: panels -> LDS (K [d][col][ks] b64; V [c][256+8] b64) ----
#pragma unroll
  for (int i = 0; i < 4; ++i) {
    int d = mg * 16 + i * 4 + kg;
    int row0 = mg * 64 + i * 16 + kg * 4;
#pragma unroll
    for (int j = 0; j < 2; ++j) {
      int col = ng * 32 + j * 16 + fr;
      u16x4 kq, vq;
#pragma unroll
      for (int rr = 0; rr < 4; ++rr) {
        kq[rr] = f2b(accK[i][j][rr] + bkr[j]);
        vq[rr] = f2b(accV[i][j][rr] + bvr[j]);
      }
      *(u16x4*)&Klds[(d * 64 + col) * 4] = kq;
      *(u16x4*)&Vlds[col * 264 + row0] = vq;
    }
  }
  __syncthreads();

  // ---- P3: QK (lane=c, wave=(p,dh)); b64 K reads ----
  float sc[4] = {0.f, 0.f, 0.f, 0.f};
#pragma unroll
  for (int dd = 0; dd < 32; ++dd) {
    int d = dh * 32 + dd;
    u32 word = qv[dd >> 3][(dd >> 1) & 3];
    float qd = (dd & 1) ? b2f_hi(word) : b2f_lo(word);
    u16x4 kv4 = *(const u16x4*)&Klds[(d * 64 + lane) * 4];
#pragma unroll
    for (int ks = 0; ks < 4; ++ks) sc[ks] += qd * b2f(kv4[ks]);
  }
  if (dh == 1) {
#pragma unroll
    for (int ks = 0; ks < 4; ++ks) Xf[(p3p * 4 + ks) * 64 + lane] = sc[ks];
  }
  __syncthreads();

  if (dh == 0) {
    float sv[4];
#pragma unroll
    for (int ks = 0; ks < 4; ++ks)
      sv[ks] = (sc[ks] + Xf[(p3p * 4 + ks) * 64 + lane]) * 0.125f + br[ks];
    float mx = fmaxf(fmaxf(sv[0], sv[1]), fmaxf(sv[2], sv[3]));
    float e0 = __expf(sv[0] - mx), e1 = __expf(sv[1] - mx), e2 = __expf(sv[2] - mx),
          e3 = __expf(sv[3] - mx);
    float inv = 1.f / (e0 + e1 + e2 + e3);
#pragma unroll
    for (int ks = 0; ks < 4; ++ks) {
      float e = (ks == 0) ? e0 : (ks == 1) ? e1 : (ks == 2) ? e2 : e3;
      alds[(p3p * 4 + ks) * 64 + lane] = e * inv;
    }
  }
  __syncthreads();

  // ---- PV: lane = out channel; wave handles its (p, c-half) ----
  float* ob = out + (size_t)(b * 32768 + p3p * 8192 + u * 512 + cg * 64) * 512 + nh * 64 + lane;
#pragma unroll
  for (int cc = 0; cc < 32; ++cc) {
    int c = dh * 32 + cc;
    u16x4 vvv = *(const u16x4*)&Vlds[c * 264 + lane * 4];
    float a0 = alds[(p3p * 4 + 0) * 64 + c];
    float a1 = alds[(p3p * 4 + 1) * 64 + c];
    float a2 = alds[(p3p * 4 + 2) * 64 + c];
    float a3 = alds[(p3p * 4 + 3) * 64 + c];
    float o = a0 * b2f(vvv[0]) + a1 * b2f(vvv[1]) + a2 * b2f(vvv[2]) + a3 * b2f(vvv[3]);
    ob[(size_t)c * 512] = o;
  }
}

// ---------------- launch ----------------
extern "C" void kernel_launch(void* const* d_in, const int* in_sizes, int n_in,
                              void* d_out, int out_size, void* d_ws, size_t ws_size,
                              hipStream_t stream) {
  (void)in_sizes; (void)n_in; (void)out_size; (void)ws_size;
  const float* s     = (const float*)d_in[0];
  const float* x     = (const float*)d_in[1];
  const float* s_pos = (const float*)d_in[2];
  const float* x_pos = (const float*)d_in[3];
  const float* Wq = (const float*)d_in[4];  const float* bq = (const float*)d_in[5];
  const float* Wk = (const float*)d_in[6];  const float* bk = (const float*)d_in[7];
  const float* Wv = (const float*)d_in[8];  const float* bv = (const float*)d_in[9];
  const float* pw1 = (const float*)d_in[10]; const float* pb1 = (const float*)d_in[11];
  const float* bng = (const float*)d_in[12]; const float* bnb = (const float*)d_in[13];
  const float* bnm = (const float*)d_in[14]; const float* bnv = (const float*)d_in[15];
  const float* pw2 = (const float*)d_in[16]; const float* pb2 = (const float*)d_in[17];
  float* out = (float*)d_out;

  char* ws = (char*)d_ws;
  u16* Qt = (u16*)ws;                        // 67,108,864 B
  float* biasw = (float*)(ws + 67108864);    //  8,388,608 B
  u16* Wt = (u16*)(ws + 75497472);           //  1,572,864 B
  u16* sbuf = (u16*)(ws + 77070336);         // 67,108,864 B (s in bf16)

  wt_kernel<<<dim3(3072), 256, 0, stream>>>(Wq, Wk, Wv, Wt);
  mid_kernel<<<dim3(18688), 256, 0, stream>>>(x, Wt, bq, Qt, s, sbuf, x_pos, s_pos, pw1, pb1,
                                              bng, bnb, bnm, bnv, pw2, pb2, biasw);
  fused_attn_kernel<<<dim3(2048), 512, 0, stream>>>(sbuf, Wt + 262144, Wt + 524288, bk, bv,
                                                    Qt, biasw, out);
}

// Round 24
// 217.341 us; speedup vs baseline: 1.0829x; 1.0034x over previous
//
#include <hip/hip_runtime.h>

// SectorAttentionV2 on MI355X (gfx950) — round 24
//   r23 + fused K-loop: removed the sched_barrier between STAGEF and the
//   ds-read/MFMA section so the compiler can interleave GLDS issue with
//   LDS reads and MFMA (AITER-style). Stage target buf and compute buf are
//   disjoint (%3 rotation), so no ordering is required between them.

typedef unsigned short u16;
typedef unsigned int u32;
typedef __attribute__((ext_vector_type(8))) short bf16x8;
typedef __attribute__((ext_vector_type(4))) float f32x4;
typedef __attribute__((ext_vector_type(8))) unsigned short u16x8;
typedef __attribute__((ext_vector_type(4))) unsigned short u16x4;
typedef __attribute__((ext_vector_type(4))) unsigned int u32x4;

__device__ __forceinline__ u16 f2b(float f) {
  u32 u = __float_as_uint(f);
  return (u16)((u + 0x7FFFu + ((u >> 16) & 1u)) >> 16);  // RNE
}
__device__ __forceinline__ float b2f(u16 v) { return __uint_as_float(((u32)v) << 16); }
__device__ __forceinline__ float b2f_lo(u32 d) { return __uint_as_float(d << 16); }
__device__ __forceinline__ float b2f_hi(u32 d) { return __uint_as_float(d & 0xffff0000u); }
__device__ __forceinline__ u32 cvt_pk(float lo, float hi) {
  u32 r;
  asm("v_cvt_pk_bf16_f32 %0, %1, %2" : "=v"(r) : "v"(lo), "v"(hi));
  return r;
}
#define GLDS(g, l)                                                                     \
  __builtin_amdgcn_global_load_lds((const __attribute__((address_space(1))) void*)(g), \
                                   (__attribute__((address_space(3))) void*)(l), 16, 0, 0)
#define SBAR() __builtin_amdgcn_sched_barrier(0)

// ---------------- wt: W[k][n] f32 -> Wt[n][k] bf16 (x3) ----------------
__global__ __launch_bounds__(256) void wt_kernel(const float* __restrict__ Wq,
                                                 const float* __restrict__ Wk,
                                                 const float* __restrict__ Wv,
                                                 u16* __restrict__ Wt) {
  int bid = (int)blockIdx.x;
  int mat = bid >> 10, bx = bid & 1023;
  const float* W = (mat == 0) ? Wq : (mat == 1) ? Wk : Wv;
  int g = bx * 256 + threadIdx.x;
  int n = g >> 9, k = g & 511;
  Wt[(size_t)mat * 262144 + g] = f2b(W[k * 512 + n]);
}

// ---------------- mid: gemm (bid<2048) + scvt (2048..18431) + bias (18432..18687) ----------------
__global__ __launch_bounds__(256, 3) void mid_kernel(
    const float* __restrict__ A, const u16* __restrict__ Bt, const float* __restrict__ biasv,
    u16* __restrict__ Out, const float* __restrict__ s, u16* __restrict__ sb,
    const float* __restrict__ xpos, const float* __restrict__ spos,
    const float* __restrict__ pw1, const float* __restrict__ pb1,
    const float* __restrict__ bng, const float* __restrict__ bnb,
    const float* __restrict__ bnm, const float* __restrict__ bnv,
    const float* __restrict__ pw2, const float* __restrict__ pb2, float* __restrict__ biasw) {
  __shared__ u16 lds[24576];
  const int bid = (int)blockIdx.x;
  const int t = threadIdx.x;

  if (bid >= 2048) {
    if (bid < 18432) {
      // ---- scvt: s f32 -> bf16 ----
      size_t i = ((size_t)(bid - 2048) * 256 + t) * 8;
      float4 v0 = *(const float4*)(s + i);
      float4 v1 = *(const float4*)(s + i + 4);
      u32x4 pk;
      pk[0] = cvt_pk(v0.x, v0.y);
      pk[1] = cvt_pk(v0.z, v0.w);
      pk[2] = cvt_pk(v1.x, v1.y);
      pk[3] = cvt_pk(v1.z, v1.w);
      *(u32x4*)(sb + i) = pk;
    } else {
      // ---- bias MLP ----
      int bx = bid - 18432;
      int wl = t & 63, p = t >> 6;
      int n = bx * 64 + wl;
      int b = n >> 13, w = n & 8191;
      float Am[16], Bm[16], Cm[16];
#pragma unroll
      for (int m = 0; m < 16; ++m) {
        float scv = bng[m] * rsqrtf(bnv[m] + 1e-5f);
        Am[m] = pw1[2 * m] * scv;
        Bm[m] = pw1[2 * m + 1] * scv;
        Cm[m] = (pb1[m] - bnm[m]) * scv + bnb[m];
      }
      size_t xi = ((size_t)(b * 32768 + p * 8192 + w)) * 2;
      float xp0 = xpos[xi], xp1 = xpos[xi + 1];
#pragma unroll
      for (int ks = 0; ks < 4; ++ks) {
        size_t si = ((size_t)((b * 4 + ks) * 8192 + w)) * 2;
        float r0 = xp0 - spos[si];
        float r1 = xp1 - spos[si + 1];
        float o[8];
#pragma unroll
        for (int oo = 0; oo < 8; ++oo) o[oo] = pb2[oo];
#pragma unroll
        for (int m = 0; m < 16; ++m) {
          float h = fmaxf(Am[m] * r0 + Bm[m] * r1 + Cm[m], 0.f);
#pragma unroll
          for (int oo = 0; oo < 8; ++oo) o[oo] += pw2[oo * 16 + m] * h;
        }
#pragma unroll
        for (int oo = 0; oo < 8; ++oo)
          biasw[((size_t)(((b * 8 + oo) * 4 + p) * 4 + ks)) * 8192 + w] = o[oo];
      }
    }
    return;
  }

  // ---- gemm role (r18/r20 proven body) ----
  const int lane = t & 63, wv = t >> 6;
  const int lg = (bid & 7) * 256 + (bid >> 3);
  const int mt = (lg >> 2) * 128, nt = (lg & 3) * 128;
  const int fr = lane & 15, kg = lane >> 4;
  const int wm = (wv & 1) * 64, wn = (wv >> 1) * 64;

  const int arow = lane >> 3;
  const int agr = (lane & 7) ^ arow;
  const int brow = lane >> 2;
  const int bgr = (lane & 3) ^ (brow & 3) ^ ((brow >> 2) & 3);

  const float* Abase = A + (size_t)mt * 512;
  const u16* Bbase = Bt + (size_t)nt * 512;

  f32x4 acc[4][4];
#pragma unroll
  for (int i = 0; i < 4; ++i)
#pragma unroll
    for (int j = 0; j < 4; ++j) acc[i][j] = (f32x4){0.f, 0.f, 0.f, 0.f};

#define STAGEQ(buf, kt)                                                       \
  {                                                                           \
    u16* Ab_ = lds + (buf)*8192;                                              \
    u16* Bb_ = lds + 16384 + (buf)*4096;                                      \
    _Pragma("unroll") for (int ii = 0; ii < 4; ++ii) {                        \
      int inst = wv * 4 + ii;                                                 \
      GLDS(Abase + (size_t)(inst * 8 + arow) * 512 + (kt) + agr * 4,          \
           Ab_ + inst * 512);                                                 \
    }                                                                         \
    _Pragma("unroll") for (int ii = 0; ii < 2; ++ii) {                        \
      int inst = wv * 2 + ii;                                                 \
      GLDS(Bbase + (size_t)(inst * 16 + brow) * 512 + (kt) + bgr * 8,         \
           Bb_ + inst * 512);                                                 \
    }                                                                         \
  }

  STAGEQ(0, 0);

  for (int ki = 0; ki < 16; ++ki) {
    int cur = ki & 1;
    if (ki < 15) {
      STAGEQ(cur ^ 1, (ki + 1) * 32);
      asm volatile("s_waitcnt vmcnt(6)" ::: "memory");
    } else {
      asm volatile("s_waitcnt vmcnt(0)" ::: "memory");
    }
    SBAR();
    __builtin_amdgcn_s_barrier();
    SBAR();

    const u16* Ab = lds + cur * 8192;
    const u16* Bb = lds + 16384 + cur * 4096;
    bf16x8 af[4], bfr[4];
#pragma unroll
    for (int i = 0; i < 4; ++i) {
      int r = wm + i * 16 + fr;
      int p0 = (2 * kg) ^ (r & 7), p1 = p0 ^ 1;
      f32x4 a0 = *(const f32x4*)&Ab[r * 64 + p0 * 8];
      f32x4 a1 = *(const f32x4*)&Ab[r * 64 + p1 * 8];
      union { bf16x8 v; u32 w[4]; } uu;
      uu.w[0] = cvt_pk(a0[0], a0[1]);
      uu.w[1] = cvt_pk(a0[2], a0[3]);
      uu.w[2] = cvt_pk(a1[0], a1[1]);
      uu.w[3] = cvt_pk(a1[2], a1[3]);
      af[i] = uu.v;
    }
#pragma unroll
    for (int j = 0; j < 4; ++j) {
      int r = wn + j * 16 + fr;
      int pos = kg ^ (r & 3) ^ ((r >> 2) & 3);
      bfr[j] = *(const bf16x8*)&Bb[r * 32 + pos * 8];
    }
    __builtin_amdgcn_s_setprio(1);
#pragma unroll
    for (int i = 0; i < 4; ++i)
#pragma unroll
      for (int j = 0; j < 4; ++j)
        acc[i][j] = __builtin_amdgcn_mfma_f32_16x16x32_bf16(af[i], bfr[j], acc[i][j], 0, 0, 0);
    __builtin_amdgcn_s_setprio(0);

    SBAR();
    __builtin_amdgcn_s_barrier();
    SBAR();
  }
#undef STAGEQ

  u16* Clds = lds;
#pragma unroll
  for (int i = 0; i < 4; ++i)
#pragma unroll
    for (int r = 0; r < 4; ++r) {
      int row = wm + i * 16 + kg * 4 + r;
#pragma unroll
      for (int j = 0; j < 4; ++j) {
        int ch = wn + j * 16 + fr;
        Clds[row * 136 + ch] = f2b(acc[i][j][r] + biasv[nt + ch]);
      }
    }
  __syncthreads();
#pragma unroll
  for (int c = 0; c < 8; ++c) {
    int off = c * 2048 + t * 8;
    int row = off >> 7, col = off & 127;
    *(u16x8*)(Out + (size_t)(mt + row) * 512 + nt + col) = *(const u16x8*)&Clds[row * 136 + col];
  }
}

// ---------------- fused KV-projection + attention (64x32 wave tiles) ----------------
// K-loop layout (bytes): S 3x16384 @0 ; W 3x8192 @49152 -> 73728
// Post-loop overlay: Xf 4096 @0 ; alds 4096 @4096 ; Klds [d][col][ks] @8192 (32768);
//                    Vlds [c][264] @40960 (33792) -> 74752 total
__global__ __launch_bounds__(512, 4) void fused_attn_kernel(
    const u16* __restrict__ sb, const u16* __restrict__ WtK, const u16* __restrict__ WtV,
    const float* __restrict__ bK, const float* __restrict__ bV,
    const u16* __restrict__ Qt, const float* __restrict__ biasw, float* __restrict__ out) {
  __shared__ __align__(16) char LDS[74752];
  float* Xf = (float*)LDS;
  float* alds = (float*)(LDS + 4096);
  u16* Klds = (u16*)(LDS + 8192);
  u16* Vlds = (u16*)(LDS + 40960);

  const int t = threadIdx.x, lane = t & 63, wv = t >> 6;
  const int i0 = (int)blockIdx.x;
  const int xcd = i0 & 7, qq = i0 >> 3;
  const int g = (qq >> 6) * 8 + xcd, inner = qq & 63;
  const int b = g >> 4, u = g & 15;
  const int cg = inner >> 3, nh = inner & 7;
  const int fr = lane & 15, kg = lane >> 4;
  const int p3p = wv >> 1, dh = wv & 1;
  const int mg = wv >> 1, ng = wv & 1;  // 4 m-groups x 2 n-groups

  f32x4 accK[4][2], accV[4][2];
#pragma unroll
  for (int i = 0; i < 4; ++i)
#pragma unroll
    for (int j = 0; j < 2; ++j) {
      accK[i][j] = (f32x4){0.f, 0.f, 0.f, 0.f};
      accV[i][j] = (f32x4){0.f, 0.f, 0.f, 0.f};
    }

  const int lgr = (lane & 3) ^ ((lane >> 3) & 3);

#define STAGEF(buf, kt)                                                                 \
  {                                                                                     \
    u16* Sb_ = (u16*)(LDS) + (buf)*8192;                                                \
    _Pragma("unroll") for (int ii = 0; ii < 2; ++ii) {                                  \
      int i = wv * 2 + ii;                                                              \
      int r = i * 16 + (lane >> 2);                                                     \
      int grow = nh * 4096 + (r >> 2) * 64 + (r & 3) * 16 + u;                          \
      GLDS(sb + (size_t)(b * 32768 + grow) * 512 + (kt) + lgr * 8, Sb_ + i * 512);      \
    }                                                                                   \
    {                                                                                   \
      const u16* wsrc = (wv < 4) ? WtK : WtV;                                           \
      u16* Wb_ = (u16*)(LDS + 49152 + (buf)*8192 + ((wv < 4) ? 0 : 4096));              \
      int i = wv & 3;                                                                   \
      int r = i * 16 + (lane >> 2);                                                     \
      GLDS(wsrc + (size_t)(cg * 64 + r) * 512 + (kt) + lgr * 8, Wb_ + i * 512);         \
    }                                                                                   \
  }

  STAGEF(0, 0);
  STAGEF(1, 32);

  for (int ki = 0; ki < 16; ++ki) {
    int cur = ki % 3;
    if (ki < 15) {
      asm volatile("s_waitcnt vmcnt(3)" ::: "memory");
    } else {
      asm volatile("s_waitcnt vmcnt(0)" ::: "memory");
    }
    SBAR();
    __builtin_amdgcn_s_barrier();
    SBAR();
    // prefetch tile ki+2 (target buf's readers all retired before this barrier).
    // NO sched_barrier after: GLDS issue may interleave with ds_reads + MFMA.
    if (ki < 14) STAGEF((ki + 2) % 3, (ki + 2) * 32);

    const u16* Sb = (const u16*)(LDS) + cur * 8192;
    const u16* Kb = (const u16*)(LDS + 49152 + cur * 8192);
    const u16* Vb = (const u16*)(LDS + 49152 + cur * 8192 + 4096);
    bf16x8 af[4];
#pragma unroll
    for (int i = 0; i < 4; ++i) {
      int r = mg * 64 + i * 16 + fr;
      int gpos = kg ^ ((fr >> 1) & 3);
      af[i] = *(const bf16x8*)&Sb[r * 32 + gpos * 8];
    }
    {
      bf16x8 bkf[2];
#pragma unroll
      for (int j = 0; j < 2; ++j) {
        int r = ng * 32 + j * 16 + fr;
        int gpos = kg ^ ((fr >> 1) & 3);
        bkf[j] = *(const bf16x8*)&Kb[r * 32 + gpos * 8];
      }
      __builtin_amdgcn_s_setprio(1);
#pragma unroll
      for (int i = 0; i < 4; ++i)
#pragma unroll
        for (int j = 0; j < 2; ++j)
          accK[i][j] = __builtin_amdgcn_mfma_f32_16x16x32_bf16(af[i], bkf[j], accK[i][j], 0, 0, 0);
      __builtin_amdgcn_s_setprio(0);
    }
    {
      bf16x8 bvf[2];
#pragma unroll
      for (int j = 0; j < 2; ++j) {
        int r = ng * 32 + j * 16 + fr;
        int gpos = kg ^ ((fr >> 1) & 3);
        bvf[j] = *(const bf16x8*)&Vb[r * 32 + gpos * 8];
      }
      __builtin_amdgcn_s_setprio(1);
#pragma unroll
      for (int i = 0; i < 4; ++i)
#pragma unroll
        for (int j = 0; j < 2; ++j)
          accV[i][j] = __builtin_amdgcn_mfma_f32_16x16x32_bf16(af[i], bvf[j], accV[i][j], 0, 0, 0);
      __builtin_amdgcn_s_setprio(0);
    }
    SBAR();
  }
#undef STAGEF

  // post-loop loads (overlap the overlay barrier)
  SBAR();
  float bkr[2], bvr[2];
#pragma unroll
  for (int j = 0; j < 2; ++j) {
    bkr[j] = bK[cg * 64 + ng * 32 + j * 16 + fr];
    bvr[j] = bV[cg * 64 + ng * 32 + j * 16 + fr];
  }
  u32x4 qv[4];
  {
    const u16* qp =
        Qt + (size_t)(b * 32768 + p3p * 8192 + u * 512 + cg * 64 + lane) * 512 + nh * 64 + dh * 32;
#pragma unroll
    for (int i = 0; i < 4; ++i) qv[i] = *(const u32x4*)(qp + i * 8);
  }
  float br[4];
  {
    const size_t bb = ((size_t)((b * 8 + nh) * 16 + p3p * 4)) * 8192 + u * 512 + cg * 64 + lane;
#pragma unroll
    for (int ks = 0; ks < 4; ++ks) br[ks] = biasw[bb + (size_t)ks * 8192];
  }
  SBAR();
  __builtin_amdgcn_s_barrier();  // overlay barrier
  SBAR();

  // ---- P2: panels -> LDS (K [d][col][ks] b64; V [c][256+8] b64) ----
#pragma unroll
  for (int i = 0; i < 4; ++i) {
    int d = mg * 16 + i * 4 + kg;
    int row0 = mg * 64 + i * 16 + kg * 4;
#pragma unroll
    for (int j = 0; j < 2; ++j) {
      int col = ng * 32 + j * 16 + fr;
      u16x4 kq, vq;
#pragma unroll
      for (int rr = 0; rr < 4; ++rr) {
        kq[rr] = f2b(accK[i][j][rr] + bkr[j]);
        vq[rr] = f2b(accV[i][j][rr] + bvr[j]);
      }
      *(u16x4*)&Klds[(d * 64 + col) * 4] = kq;
      *(u16x4*)&Vlds[col * 264 + row0] = vq;
    }
  }
  __syncthreads();

  // ---- P3: QK (lane=c, wave=(p,dh)); b64 K reads ----
  float sc[4] = {0.f, 0.f, 0.f, 0.f};
#pragma unroll
  for (int dd = 0; dd < 32; ++dd) {
    int d = dh * 32 + dd;
    u32 word = qv[dd >> 3][(dd >> 1) & 3];
    float qd = (dd & 1) ? b2f_hi(word) : b2f_lo(word);
    u16x4 kv4 = *(const u16x4*)&Klds[(d * 64 + lane) * 4];
#pragma unroll
    for (int ks = 0; ks < 4; ++ks) sc[ks] += qd * b2f(kv4[ks]);
  }
  if (dh == 1) {
#pragma unroll
    for (int ks = 0; ks < 4; ++ks) Xf[(p3p * 4 + ks) * 64 + lane] = sc[ks];
  }
  __syncthreads();

  if (dh == 0) {
    float sv[4];
#pragma unroll
    for (int ks = 0; ks < 4; ++ks)
      sv[ks] = (sc[ks] + Xf[(p3p * 4 + ks) * 64 + lane]) * 0.125f + br[ks];
    float mx = fmaxf(fmaxf(sv[0], sv[1]), fmaxf(sv[2], sv[3]));
    float e0 = __expf(sv[0] - mx), e1 = __expf(sv[1] - mx), e2 = __expf(sv[2] - mx),
          e3 = __expf(sv[3] - mx);
    float inv = 1.f / (e0 + e1 + e2 + e3);
#pragma unroll
    for (int ks = 0; ks < 4; ++ks) {
      float e = (ks == 0) ? e0 : (ks == 1) ? e1 : (ks == 2) ? e2 : e3;
      alds[(p3p * 4 + ks) * 64 + lane] = e * inv;
    }
  }
  __syncthreads();

  // ---- PV: lane = out channel; wave handles its (p, c-half) ----
  float* ob = out + (size_t)(b * 32768 + p3p * 8192 + u * 512 + cg * 64) * 512 + nh * 64 + lane;
#pragma unroll
  for (int cc = 0; cc < 32; ++cc) {
    int c = dh * 32 + cc;
    u16x4 vvv = *(const u16x4*)&Vlds[c * 264 + lane * 4];
    float a0 = alds[(p3p * 4 + 0) * 64 + c];
    float a1 = alds[(p3p * 4 + 1) * 64 + c];
    float a2 = alds[(p3p * 4 + 2) * 64 + c];
    float a3 = alds[(p3p * 4 + 3) * 64 + c];
    float o = a0 * b2f(vvv[0]) + a1 * b2f(vvv[1]) + a2 * b2f(vvv[2]) + a3 * b2f(vvv[3]);
    ob[(size_t)c * 512] = o;
  }
}

// ---------------- launch ----------------
extern "C" void kernel_launch(void* const* d_in, const int* in_sizes, int n_in,
                              void* d_out, int out_size, void* d_ws, size_t ws_size,
                              hipStream_t stream) {
  (void)in_sizes; (void)n_in; (void)out_size; (void)ws_size;
  const float* s     = (const float*)d_in[0];
  const float* x     = (const float*)d_in[1];
  const float* s_pos = (const float*)d_in[2];
  const float* x_pos = (const float*)d_in[3];
  const float* Wq = (const float*)d_in[4];  const float* bq = (const float*)d_in[5];
  const float* Wk = (const float*)d_in[6];  const float* bk = (const float*)d_in[7];
  const float* Wv = (const float*)d_in[8];  const float* bv = (const float*)d_in[9];
  const float* pw1 = (const float*)d_in[10]; const float* pb1 = (const float*)d_in[11];
  const float* bng = (const float*)d_in[12]; const float* bnb = (const float*)d_in[13];
  const float* bnm = (const float*)d_in[14]; const float* bnv = (const float*)d_in[15];
  const float* pw2 = (const float*)d_in[16]; const float* pb2 = (const float*)d_in[17];
  float* out = (float*)d_out;

  char* ws = (char*)d_ws;
  u16* Qt = (u16*)ws;                        // 67,108,864 B
  float* biasw = (float*)(ws + 67108864);    //  8,388,608 B
  u16* Wt = (u16*)(ws + 75497472);           //  1,572,864 B
  u16* sbuf = (u16*)(ws + 77070336);         // 67,108,864 B (s in bf16)

  wt_kernel<<<dim3(3072), 256, 0, stream>>>(Wq, Wk, Wv, Wt);
  mid_kernel<<<dim3(18688), 256, 0, stream>>>(x, Wt, bq, Qt, s, sbuf, x_pos, s_pos, pw1, pb1,
                                              bng, bnb, bnm, bnv, pw2, pb2, biasw);
  fused_attn_kernel<<<dim3(2048), 512, 0, stream>>>(sbuf, Wt + 262144, Wt + 524288, bk, bv,
                                                    Qt, biasw, out);
}